// Round 7
// baseline (683.397 us; speedup 1.0000x reference)
//
#include <hip/hip_runtime.h>
#include <math.h>

#define NB   16      // batch
#define SEQL 197     // sequence length (196 patches + cls)
#define TB   (NB*SEQL)   // 3152 tokens
#define DIMM 256
#define DI   512
#define DS   16
#define NL   8

typedef __bf16 bf16x8 __attribute__((ext_vector_type(8)));
typedef __bf16 bf16x4 __attribute__((ext_vector_type(4)));
typedef float floatx4 __attribute__((ext_vector_type(4)));

// ---------------- block-wide 2-value reduction (256 threads = 4 waves) -----
__device__ __forceinline__ void block_reduce_2(float& s1, float& s2, float* red, int tid){
  #pragma unroll
  for (int off = 32; off > 0; off >>= 1){
    s1 += __shfl_down(s1, off, 64);
    s2 += __shfl_down(s2, off, 64);
  }
  __syncthreads();
  if ((tid & 63) == 0){ red[(tid>>6)*2] = s1; red[(tid>>6)*2+1] = s2; }
  __syncthreads();
  s1 = red[0] + red[2] + red[4] + red[6];
  s2 = red[1] + red[3] + red[5] + red[7];
}

// ---------------- merged weight prep: all transposes in ONE dispatch -------
// bf16 ranges: in[K][Nin] fp32 -> out[Nin][K] bf16.
// xproj range: in[512][48] fp32 -> out k4-packed fp32 [128][64][4]:
//   element (k,col) at (k>>2)*256 + col*4 + (k&3); cols 48..63 zero.
// Block ranges: [0,2048) in_w | [2048,3072) out_w | [3072,3264) pe_w |
//               [3264,3520) xproj
__global__ __launch_bounds__(256) void prep_weights(
    const float* __restrict__ in_w, const float* __restrict__ out_w,
    const float* __restrict__ pe_w, const float* __restrict__ xproj,
    __bf16* __restrict__ wt_in, __bf16* __restrict__ wt_out,
    __bf16* __restrict__ wt_pe, float* __restrict__ wt_xp_f)
{
  __shared__ float t[32][33];
  int bid = blockIdx.x;
  const float* src; __bf16* dst = nullptr; float* dstf = nullptr;
  int K, Nin, n0, k0;
  if (bid < 2048){                       // in_w: 8 z * (32 n-tiles * 8 k-tiles)
    int z = bid >> 8, tt = bid & 255;
    K = 256; Nin = 1024; n0 = (tt & 31)*32; k0 = (tt >> 5)*32;
    src = in_w  + (size_t)z*K*Nin;
    dst = wt_in + (size_t)z*K*Nin;
  } else if (bid < 3072){                // out_w: 8 z * (8 n-tiles * 16 k-tiles)
    int t2 = bid - 2048; int z = t2 >> 7, tt = t2 & 127;
    K = 512; Nin = 256; n0 = (tt & 7)*32; k0 = (tt >> 3)*32;
    src = out_w  + (size_t)z*K*Nin;
    dst = wt_out + (size_t)z*K*Nin;
  } else if (bid < 3264){                // pe_w: 8 n-tiles * 24 k-tiles
    int tt = bid - 3072;
    K = 768; Nin = 256; n0 = (tt & 7)*32; k0 = (tt >> 3)*32;
    src = pe_w; dst = wt_pe;
  } else {                               // xproj: 8 z * (2 n-tiles * 16 k-tiles)
    int t2 = bid - 3264; int z = t2 >> 5, tt = t2 & 31;
    K = 512; Nin = 48; n0 = (tt & 1)*32; k0 = (tt >> 1)*32;
    src  = xproj + (size_t)z*K*Nin;
    dstf = wt_xp_f + (size_t)z*64*512;
  }
  int tx = threadIdx.x & 31, ty = threadIdx.x >> 5;
  #pragma unroll
  for (int j = 0; j < 4; j++){
    int n = n0 + tx;
    t[ty + j*8][tx] = (n < Nin) ? src[(size_t)(k0 + ty + j*8)*Nin + n] : 0.f;
  }
  __syncthreads();
  if (dstf){
    #pragma unroll
    for (int j = 0; j < 4; j++){
      int k = k0 + tx, c = n0 + ty + j*8;
      dstf[(size_t)(k>>2)*256 + c*4 + (k&3)] = t[tx][ty + j*8];
    }
  } else {
    #pragma unroll
    for (int j = 0; j < 4; j++)
      dst[(size_t)(n0 + ty + j*8)*K + k0 + tx] = (__bf16)t[tx][ty + j*8];
  }
}

// ---------------- bf16 MFMA GEMM: C fp32 = A[M][K] @ Wt[N][K]^T (+bias) ----
// R7: BK=64 (half the K-iterations of the R6 BK=32 loop) + register
// prefetch: next iteration's global loads are issued BEFORE the MFMA phase
// so HBM latency overlaps compute+barrier. MFMA order identical to BK=32
// (ascending 32-wide chunks) -> bit-identical results.
template<int BM, int BN, int BK>
__global__ __launch_bounds__(256) void gemm_bf16(
    const __bf16* __restrict__ A, const __bf16* __restrict__ Wt,
    const float* __restrict__ bias, float* __restrict__ C, int M, int N, int K)
{
  constexpr int LDA = BK + 8;
  constexpr int TMW = BM/32;
  constexpr int TNW = BN/32;
  constexpr int KU  = BK/8;            // uint4 per row
  constexpr int NA  = BM*KU/256;       // uint4 per thread (A)
  constexpr int NBu = BN*KU/256;       // uint4 per thread (B)
  __shared__ __bf16 As[BM][LDA];
  __shared__ __bf16 Bs[BN][LDA];

  int tid  = threadIdx.x;
  int lane = tid & 63, w = tid >> 6;
  int wm = w >> 1, wn = w & 1;
  int l15 = lane & 15, quad = lane >> 4;
  int bm = blockIdx.y * BM, bn = blockIdx.x * BN;

  floatx4 acc[TMW][TNW] = {};
  uint4 pa[NA], pb[NBu];

  auto load_regs = [&](int k0){
    #pragma unroll
    for (int i = 0; i < NA; i++){
      int c = tid + i*256;
      int row = c / KU, kc = c % KU;
      int m = bm + row;
      pa[i] = make_uint4(0,0,0,0);
      if (m < M) pa[i] = ((const uint4*)(A + (size_t)m*K + k0))[kc];
    }
    #pragma unroll
    for (int i = 0; i < NBu; i++){
      int c = tid + i*256;
      int row = c / KU, kc = c % KU;
      pb[i] = ((const uint4*)(Wt + (size_t)(bn + row)*K + k0))[kc];
    }
  };
  auto store_lds = [&](){
    #pragma unroll
    for (int i = 0; i < NA; i++){
      int c = tid + i*256;
      *(uint4*)&As[c / KU][(c % KU)*8] = pa[i];
    }
    #pragma unroll
    for (int i = 0; i < NBu; i++){
      int c = tid + i*256;
      *(uint4*)&Bs[c / KU][(c % KU)*8] = pb[i];
    }
  };

  load_regs(0);
  for (int k0 = 0; k0 < K; k0 += BK){
    store_lds();
    __syncthreads();
    if (k0 + BK < K) load_regs(k0 + BK);   // prefetch in flight over MFMA
    #pragma unroll
    for (int kk = 0; kk < BK/32; kk++){
      bf16x8 af[TMW], bf[TNW];
      #pragma unroll
      for (int mi = 0; mi < TMW; mi++)
        af[mi] = *(const bf16x8*)&As[wm*(BM/2) + mi*16 + l15][kk*32 + quad*8];
      #pragma unroll
      for (int ni = 0; ni < TNW; ni++)
        bf[ni] = *(const bf16x8*)&Bs[wn*(BN/2) + ni*16 + l15][kk*32 + quad*8];
      #pragma unroll
      for (int mi = 0; mi < TMW; mi++)
        #pragma unroll
        for (int ni = 0; ni < TNW; ni++)
          acc[mi][ni] = __builtin_amdgcn_mfma_f32_16x16x32_bf16(af[mi], bf[ni], acc[mi][ni], 0, 0, 0);
    }
    __syncthreads();
  }
  #pragma unroll
  for (int mi = 0; mi < TMW; mi++){
    #pragma unroll
    for (int ni = 0; ni < TNW; ni++){
      int col = bn + wn*(BN/2) + ni*16 + l15;
      float bv = bias ? bias[col] : 0.f;
      #pragma unroll
      for (int r = 0; r < 4; r++){
        int row = bm + wm*(BM/2) + mi*16 + quad*4 + r;
        if (row < M) C[(size_t)row*N + col] = acc[mi][ni][r] + bv;
      }
    }
  }
}

// ---------------- fused out-proj GEMM + residual add + next-layer LN -------
// y[16][256] = A[bm:bm+16][512] @ Wt[256][512]^T ; resid += y ;
// DO_LN: xn_bf = LN(resid)*g + b (bf16). 512 threads (8 waves), BK=64.
template<int DO_LN>
__global__ __launch_bounds__(512) void gemm_out_fused(
    const __bf16* __restrict__ A, const __bf16* __restrict__ Wt,
    float* __restrict__ resid, __bf16* __restrict__ xn_bf,
    const float* __restrict__ g, const float* __restrict__ bta)
{
  constexpr int BK = 64, LDA = BK + 8;      // 72
  __shared__ alignas(16) char smem[(16 + 256) * LDA * sizeof(__bf16)]; // 39168B
  __bf16 (*As)[LDA] = (__bf16(*)[LDA])smem;
  __bf16 (*Bs)[LDA] = (__bf16(*)[LDA])(smem + 16*LDA*sizeof(__bf16));
  float  (*sy)[264] = (float(*)[264])smem;  // union reuse: 16*264*4 = 16896B

  int tid = threadIdx.x, lane = tid & 63, w = tid >> 6;   // w in 0..7
  int l15 = lane & 15, quad = lane >> 4;
  int bm = blockIdx.x * 16;

  floatx4 acc[2] = {};
  for (int k0 = 0; k0 < 512; k0 += BK){
    if (tid < 128){                        // A: 16 rows x 8 uint4
      int row = tid >> 3, kc = tid & 7;
      *(uint4*)&As[row][kc*8] = ((const uint4*)(A + (size_t)(bm+row)*512 + k0))[kc];
    }
    #pragma unroll
    for (int i = 0; i < 4; i++){           // B: 256 rows x 8 uint4 = 2048
      int c = tid + i*512;
      int row = c >> 3, kc = c & 7;
      *(uint4*)&Bs[row][kc*8] = ((const uint4*)(Wt + (size_t)row*512 + k0))[kc];
    }
    __syncthreads();
    #pragma unroll
    for (int kk = 0; kk < 2; kk++){
      bf16x8 af = *(const bf16x8*)&As[l15][kk*32 + quad*8];
      #pragma unroll
      for (int ni = 0; ni < 2; ni++){
        bf16x8 bfv = *(const bf16x8*)&Bs[w*32 + ni*16 + l15][kk*32 + quad*8];
        acc[ni] = __builtin_amdgcn_mfma_f32_16x16x32_bf16(af, bfv, acc[ni], 0, 0, 0);
      }
    }
    __syncthreads();
  }
  // dump fragments to LDS (rows = quad*4+r, cols = w*32 + ni*16 + l15)
  #pragma unroll
  for (int ni = 0; ni < 2; ni++){
    int col = w*32 + ni*16 + l15;
    #pragma unroll
    for (int r = 0; r < 4; r++)
      sy[quad*4 + r][col] = acc[ni][r];
  }
  __syncthreads();
  // row-major pass: wave w owns rows w*2, w*2+1; coalesced float4
  #pragma unroll
  for (int rr = 0; rr < 2; rr++){
    int row = w*2 + rr;
    size_t base = (size_t)(bm + row)*256 + lane*4;
    float4 y4 = *(const float4*)&sy[row][lane*4];
    float4 rv = *(const float4*)&resid[base];
    float4 v;
    v.x = y4.x + rv.x; v.y = y4.y + rv.y; v.z = y4.z + rv.z; v.w = y4.w + rv.w;
    *(float4*)&resid[base] = v;
    if (DO_LN){
      float s  = v.x + v.y + v.z + v.w;
      float s2 = v.x*v.x + v.y*v.y + v.z*v.z + v.w*v.w;
      #pragma unroll
      for (int off = 1; off < 64; off <<= 1){
        s  += __shfl_xor(s,  off, 64);
        s2 += __shfl_xor(s2, off, 64);
      }
      float mu  = s * (1.f/256.f);
      float var = s2 * (1.f/256.f) - mu*mu;
      float rrq = rsqrtf(var + 1e-5f);
      float4 gv = *(const float4*)&g[lane*4];
      float4 bv = *(const float4*)&bta[lane*4];
      bf16x4 o;
      o[0] = (__bf16)((v.x - mu)*rrq*gv.x + bv.x);
      o[1] = (__bf16)((v.y - mu)*rrq*gv.y + bv.y);
      o[2] = (__bf16)((v.z - mu)*rrq*gv.z + bv.z);
      o[3] = (__bf16)((v.w - mu)*rrq*gv.w + bv.w);
      *(bf16x4*)&xn_bf[base] = o;
    }
  }
}

// ---------------- patch LN1: gather + LayerNorm(768) -> bf16 ---------------
// R7: tid <-> (p1 = tid>>4, p2 = tid&15), loop over channel c. Lanes read
// 16-float contiguous runs (64B segments) -> coalesced, vs the old
// channel-fastest map (consecutive lanes 200 KB apart). Output e = tid*3+c.
__global__ __launch_bounds__(256) void patch_ln1(
    const float* __restrict__ img, const float* __restrict__ g1, const float* __restrict__ b1,
    __bf16* __restrict__ xp_bf)
{
  __shared__ float red[8];
  int blk = blockIdx.x;            // b*196 + patch
  int b = blk / 196, p = blk % 196;
  int hh = p / 14, ww = p % 14;
  int tid = threadIdx.x;

  const float* ip = img + ((size_t)(b*3)*224 + hh*16 + (tid>>4))*224 + ww*16 + (tid&15);
  float v[3]; float s = 0.f, s2 = 0.f;
  #pragma unroll
  for (int c = 0; c < 3; c++){
    float val = ip[(size_t)c*224*224];
    v[c] = val; s += val; s2 += val*val;
  }
  block_reduce_2(s, s2, red, tid);
  float mu = s * (1.f/768.f);
  float var = s2 * (1.f/768.f) - mu*mu;
  float rr = rsqrtf(var + 1e-5f);
  #pragma unroll
  for (int c = 0; c < 3; c++){
    int e = tid*3 + c;
    xp_bf[(size_t)blk*768 + e] = (__bf16)((v[c] - mu) * rr * g1[e] + b1[e]);
  }
}

// ---------------- patch LN2 + pos + cls + layer-0 LN, wave-per-token -------
// R7: 788 blocks x 4 waves; each wave owns one token (64 lanes x float4).
// Pure-shfl reductions, zero barriers. Writes resid + xn_bf.
__global__ __launch_bounds__(256) void ln2_cls_pos(
    const float* __restrict__ pemb, const float* __restrict__ g2, const float* __restrict__ b2,
    const float* __restrict__ pos, const float* __restrict__ cls,
    float* __restrict__ resid,
    const float* __restrict__ g0, const float* __restrict__ b0,
    __bf16* __restrict__ xn_bf)
{
  int w = threadIdx.x >> 6, lane = threadIdx.x & 63;
  int blk = blockIdx.x*4 + w;      // token id
  int b = blk / SEQL, l = blk % SEQL;
  int e = lane*4;
  float4 o;
  if (l == 0){
    float4 cv = *(const float4*)&cls[e];
    float4 pv = *(const float4*)&pos[e];
    o.x = cv.x + pv.x; o.y = cv.y + pv.y; o.z = cv.z + pv.z; o.w = cv.w + pv.w;
  } else {
    float4 v = *(const float4*)&pemb[(size_t)(b*196 + l-1)*256 + e];
    float s  = v.x + v.y + v.z + v.w;
    float s2 = v.x*v.x + v.y*v.y + v.z*v.z + v.w*v.w;
    #pragma unroll
    for (int off = 1; off < 64; off <<= 1){
      s  += __shfl_xor(s,  off, 64);
      s2 += __shfl_xor(s2, off, 64);
    }
    float mu  = s * (1.f/256.f);
    float var = s2 * (1.f/256.f) - mu*mu;
    float rr  = rsqrtf(var + 1e-5f);
    float4 gv = *(const float4*)&g2[e];
    float4 bv = *(const float4*)&b2[e];
    float4 pv = *(const float4*)&pos[l*256 + e];
    o.x = (v.x - mu)*rr*gv.x + bv.x + pv.x;
    o.y = (v.y - mu)*rr*gv.y + bv.y + pv.y;
    o.z = (v.z - mu)*rr*gv.z + bv.z + pv.z;
    o.w = (v.w - mu)*rr*gv.w + bv.w + pv.w;
  }
  size_t idx = (size_t)blk*256 + e;
  *(float4*)&resid[idx] = o;
  // layer-0 LN
  float s  = o.x + o.y + o.z + o.w;
  float s2 = o.x*o.x + o.y*o.y + o.z*o.z + o.w*o.w;
  #pragma unroll
  for (int off = 1; off < 64; off <<= 1){
    s  += __shfl_xor(s,  off, 64);
    s2 += __shfl_xor(s2, off, 64);
  }
  float mu  = s * (1.f/256.f);
  float var = s2 * (1.f/256.f) - mu*mu;
  float rr  = rsqrtf(var + 1e-5f);
  float4 gv = *(const float4*)&g0[e];
  float4 bv = *(const float4*)&b0[e];
  bf16x4 ob;
  ob[0] = (__bf16)((o.x - mu)*rr*gv.x + bv.x);
  ob[1] = (__bf16)((o.y - mu)*rr*gv.y + bv.y);
  ob[2] = (__bf16)((o.z - mu)*rr*gv.z + bv.z);
  ob[3] = (__bf16)((o.w - mu)*rr*gv.w + bv.w);
  *(bf16x4*)&xn_bf[idx] = ob;
}

// ---------------- FUSED causal conv(k=4)+SiLU + xproj matvec (R6) ----------
// Block = 8 tokens, 256 threads. Phase 1: conv+SiLU -> u (global) + LDS,
// sliding-window history in registers (7 global loads/thread vs 16).
// Phase 2: dbc[t][0:48] = u[t][:] @ xproj, k4-packed coalesced weight.
__global__ __launch_bounds__(256) void conv_xproj(
    const float* __restrict__ xz, const float* __restrict__ cw, const float* __restrict__ cb,
    const float* __restrict__ wxp,
    float* __restrict__ u, float* __restrict__ dbc)
{
  __shared__ float s_u[8][512];         // 16 KB
  __shared__ float s_acc[4][8][64];     // 8 KB
  int tid = threadIdx.x;
  int t0 = blockIdx.x * 8;

  // ---- phase 1: conv + silu, sliding window ----
  int d = (tid & 127) * 4;
  float4 w0 = *(const float4*)&cw[(d+0)*4];
  float4 w1 = *(const float4*)&cw[(d+1)*4];
  float4 w2 = *(const float4*)&cw[(d+2)*4];
  float4 w3 = *(const float4*)&cw[(d+3)*4];
  float4 cbv = *(const float4*)&cb[d];
  const float4 z4 = make_float4(0.f,0.f,0.f,0.f);
  int tt0 = t0 + (tid >> 7)*4;          // first of this thread's 4 tokens
  float4 h1 = (tt0 >= 1) ? *(const float4*)&xz[(size_t)(tt0-1)*1024 + d] : z4;
  float4 h2 = (tt0 >= 2) ? *(const float4*)&xz[(size_t)(tt0-2)*1024 + d] : z4;
  float4 h3 = (tt0 >= 3) ? *(const float4*)&xz[(size_t)(tt0-3)*1024 + d] : z4;
  int l0 = tt0 % SEQL;
  #pragma unroll
  for (int j = 0; j < 4; j++){
    int t = tt0 + j;
    int l = l0 + j; if (l >= SEQL) l -= SEQL;
    float4 x0 = *(const float4*)&xz[(size_t)t*1024 + d];
    float4 x1 = (l>=1) ? h1 : z4;
    float4 x2 = (l>=2) ? h2 : z4;
    float4 x3 = (l>=3) ? h3 : z4;
    float4 r = cbv;
    r.x += x3.x*w0.x + x2.x*w0.y + x1.x*w0.z + x0.x*w0.w;
    r.y += x3.y*w1.x + x2.y*w1.y + x1.y*w1.z + x0.y*w1.w;
    r.z += x3.z*w2.x + x2.z*w2.y + x1.z*w2.z + x0.z*w2.w;
    r.w += x3.w*w3.x + x2.w*w3.y + x1.w*w3.z + x0.w*w3.w;
    r.x *= 1.f/(1.f + __expf(-r.x));
    r.y *= 1.f/(1.f + __expf(-r.y));
    r.z *= 1.f/(1.f + __expf(-r.z));
    r.w *= 1.f/(1.f + __expf(-r.w));
    *(float4*)&u[(size_t)t*512 + d] = r;
    *(float4*)&s_u[(tid>>7)*4 + j][d] = r;
    h3 = h2; h2 = h1; h1 = x0;
  }
  __syncthreads();

  // ---- phase 2: xproj matvec; wave = one 128-wide k-slice, lane = col ----
  int col = tid & 63, sl = tid >> 6;
  const float4* wp4 = (const float4*)wxp + (size_t)sl*32*64 + col;
  float a[8] = {};
  #pragma unroll 4
  for (int k4 = 0; k4 < 32; k4++){
    float4 wv = wp4[(size_t)k4*64];
    #pragma unroll
    for (int t = 0; t < 8; t++){
      float4 v = *(const float4*)&s_u[t][sl*128 + k4*4];
      a[t] += wv.x*v.x + wv.y*v.y + wv.z*v.z + wv.w*v.w;
    }
  }
  #pragma unroll
  for (int t = 0; t < 8; t++) s_acc[sl][t][col] = a[t];
  __syncthreads();
  #pragma unroll
  for (int j = 0; j < 2; j++){
    int p = tid + j*256;
    int tok = p >> 6, c2 = p & 63;
    if (c2 < 48){
      float v = s_acc[0][tok][c2] + s_acc[1][tok][c2]
              + s_acc[2][tok][c2] + s_acc[3][tok][c2];
      dbc[(size_t)(t0 + tok)*64 + c2] = v;
    }
  }
}

// ---------------- selective scan + fused dtproj/softplus (R3/R8) -----------
// dbc is [TB][64]: cols 0:16 dt_in, 16:32 B, 32:48 C.
#define SCT 32
#define NCH ((SEQL + SCT - 1)/SCT)   // 7
#define NDL 8                        // d-channels per block
__global__ __launch_bounds__(128) void scan_kernel(
    const float* __restrict__ u, const float* __restrict__ dbc,
    const float* __restrict__ xz, const float* __restrict__ A_log, const float* __restrict__ Dp,
    const float* __restrict__ dtw, const float* __restrict__ dtb,
    __bf16* __restrict__ yg_bf)
{
  __shared__ float s_D [16][36];        // dt_in  [k][tl]
  __shared__ float s_B [16][36];        // B      [n][tl]
  __shared__ float s_C [16][36];        // C      [n][tl]
  __shared__ float s_u [NDL][36];       // u      [dl][tl]
  __shared__ float s_z [NDL][36];       // z      [dl][tl]
  __shared__ float s_dt[NDL][36];       // softplus dt [dl][tl]
  __shared__ float s_yp[SCT][NDL][20];  // y partials [tl][dl][n]
  __shared__ float s_dp[NDL];

  int tid = threadIdx.x;                // 0..127 = dl*16 + n
  int n = tid & 15, dl = tid >> 4;      // dl 0..7
  int b = blockIdx.x >> 6, dg = blockIdx.x & 63;
  int d0 = dg * NDL;
  const size_t base = (size_t)b * SEQL;

  float A = -__expf(A_log[(d0+dl)*DS + n]);
  float h = 0.f;
  if (tid < NDL) s_dp[tid] = Dp[d0 + tid];
  int cch = tid & 7;                    // dt-proj output channel for this thread
  float wc[16];
  #pragma unroll
  for (int k = 0; k < 16; k++) wc[k] = dtw[k*512 + d0 + cch];
  float dtbv = dtb[d0 + cch];

  float r_u[2], r_z[2], r_db[12];
  auto load_regs = [&](int c){
    #pragma unroll
    for (int i = 0; i < 2; i++){
      int v = tid + i*128;
      int tg = c*SCT + (v>>3); if (tg > SEQL-1) tg = SEQL-1;
      size_t t = base + tg;
      r_u[i] = u [t*512 + d0 + (v&7)];
      r_z[i] = xz[t*1024 + 512 + d0 + (v&7)];
    }
    #pragma unroll
    for (int s = 0; s < 3; s++)
      #pragma unroll
      for (int i = 0; i < 4; i++){
        int v = tid + i*128;
        int tg = c*SCT + (v>>4); if (tg > SEQL-1) tg = SEQL-1;
        r_db[s*4+i] = dbc[(base + tg)*64 + s*16 + (v&15)];
      }
  };
  auto write_DBC = [&](){
    #pragma unroll
    for (int i = 0; i < 4; i++){
      int v = tid + i*128;
      s_D[v&15][v>>4] = r_db[0+i];
      s_B[v&15][v>>4] = r_db[4+i];
      s_C[v&15][v>>4] = r_db[8+i];
    }
  };
  auto write_UZ = [&](){
    #pragma unroll
    for (int i = 0; i < 2; i++){
      int v = tid + i*128;
      s_u[v&7][v>>3] = r_u[i];
      s_z[v&7][v>>3] = r_z[i];
    }
  };
  auto compute_dt = [&](){
    #pragma unroll
    for (int i = 0; i < 2; i++){
      int tl = (tid >> 3) + i*16;
      float acc = dtbv;
      #pragma unroll
      for (int k = 0; k < 16; k++) acc += s_D[k][tl] * wc[k];
      s_dt[cch][tl] = (acc > 20.f) ? acc : log1pf(__expf(acc));
    }
  };

  // prologue: stage chunk 0
  load_regs(0);
  write_DBC();
  write_UZ();
  __syncthreads();
  compute_dt();
  __syncthreads();

  for (int c = 0; c < NCH; c++){
    if (c + 1 < NCH) load_regs(c+1);        // global loads in flight over compute

    // ---- hot loop: 32 steps, unrolled, no cross-lane deps ----
    float4 dt4, u4, B4, C4;
    #pragma unroll
    for (int tl = 0; tl < SCT; tl++){
      if ((tl & 3) == 0){
        dt4 = *(const float4*)&s_dt[dl][tl];
        u4  = *(const float4*)&s_u [dl][tl];
        B4  = *(const float4*)&s_B [n][tl];
        C4  = *(const float4*)&s_C [n][tl];
      }
      float dtv = ((float*)&dt4)[tl&3];
      float uv  = ((float*)&u4 )[tl&3];
      float Bv  = ((float*)&B4 )[tl&3];
      float Cv  = ((float*)&C4 )[tl&3];
      h = __expf(dtv * A) * h + (dtv * uv) * Bv;
      s_yp[tl][dl][n] = h * Cv;
    }
    __syncthreads();                         // (1) y-partials visible

    if (c + 1 < NCH) write_DBC();            // stage next D/B/C

    // ---- reduction + gate + store ----
    #pragma unroll
    for (int j = 0; j < 2; j++){
      int p = tid + j*128;
      int tl = p >> 3, dr = p & 7;
      float4 a0 = *(const float4*)&s_yp[tl][dr][0];
      float4 a1 = *(const float4*)&s_yp[tl][dr][4];
      float4 a2 = *(const float4*)&s_yp[tl][dr][8];
      float4 a3 = *(const float4*)&s_yp[tl][dr][12];
      float yv = ((a0.x+a0.y)+(a0.z+a0.w)) + ((a1.x+a1.y)+(a1.z+a1.w))
               + ((a2.x+a2.y)+(a2.z+a2.w)) + ((a3.x+a3.y)+(a3.z+a3.w));
      int tg = c*SCT + tl;
      if (tg < SEQL){
        float uv = s_u[dr][tl];
        float zv = s_z[dr][tl];
        float sg = 1.f / (1.f + __expf(-zv));
        yg_bf[(base + tg)*512 + d0 + dr] = (__bf16)((yv + uv*s_dp[dr]) * zv * sg);
      }
    }
    __syncthreads();                         // (2) u/z reads done; s_D complete

    if (c + 1 < NCH){
      write_UZ();
      compute_dt();
      __syncthreads();                       // (3) s_dt/s_u/s_z ready
    }
  }
}

// ---------------- FUSED final LN (token 0) + head GEMM (R6) ----------------
__global__ __launch_bounds__(256) void final_head(
    const float* __restrict__ resid,
    const float* __restrict__ g, const float* __restrict__ bta,
    const float* __restrict__ head_w, const float* __restrict__ head_b,
    float* __restrict__ out)
{
  __shared__ float xs[16][256];
  int tid = threadIdx.x, lane = tid & 63, w = tid >> 6;
  #pragma unroll
  for (int rb = 0; rb < 4; rb++){
    int b = w + rb*4;
    const float* rp = resid + (size_t)b*SEQL*256;   // token 0
    float4 v = *(const float4*)&rp[lane*4];
    float s  = v.x + v.y + v.z + v.w;
    float s2 = v.x*v.x + v.y*v.y + v.z*v.z + v.w*v.w;
    #pragma unroll
    for (int off = 1; off < 64; off <<= 1){
      s  += __shfl_xor(s,  off, 64);
      s2 += __shfl_xor(s2, off, 64);
    }
    float mu  = s * (1.f/256.f);
    float var = s2 * (1.f/256.f) - mu*mu;
    float rr  = rsqrtf(var + 1e-5f);
    float4 gv = *(const float4*)&g[lane*4];
    float4 bv = *(const float4*)&bta[lane*4];
    xs[b][lane*4+0] = (v.x - mu)*rr*gv.x + bv.x;
    xs[b][lane*4+1] = (v.y - mu)*rr*gv.y + bv.y;
    xs[b][lane*4+2] = (v.z - mu)*rr*gv.z + bv.z;
    xs[b][lane*4+3] = (v.w - mu)*rr*gv.w + bv.w;
  }
  __syncthreads();
  int nl = tid & 31, bq = tid >> 5;
  int nn = blockIdx.x*32 + nl;
  if (nn >= 1000) return;
  float acc0 = 0.f, acc1 = 0.f;
  #pragma unroll 8
  for (int k = 0; k < 256; k++){
    float wv = head_w[k*1000 + nn];
    acc0 += xs[bq][k]   * wv;
    acc1 += xs[bq+8][k] * wv;
  }
  float hb = head_b[nn];
  out[(size_t)bq*1000 + nn]     = acc0 + hb;
  out[(size_t)(bq+8)*1000 + nn] = acc1 + hb;
}

// ---------------------------------------------------------------------------
extern "C" void kernel_launch(void* const* d_in, const int* in_sizes, int n_in,
                              void* d_out, int out_size, void* d_ws, size_t ws_size,
                              hipStream_t stream) {
  const float* img   = (const float*)d_in[0];
  const float* ln1g  = (const float*)d_in[1];
  const float* ln1b  = (const float*)d_in[2];
  const float* pe_w  = (const float*)d_in[3];
  const float* pe_b  = (const float*)d_in[4];
  const float* ln2g  = (const float*)d_in[5];
  const float* ln2b  = (const float*)d_in[6];
  const float* pos   = (const float*)d_in[7];
  const float* cls   = (const float*)d_in[8];
  const float* ln_w  = (const float*)d_in[9];
  const float* ln_b  = (const float*)d_in[10];
  const float* in_w  = (const float*)d_in[11];
  const float* conv_w= (const float*)d_in[12];
  const float* conv_b= (const float*)d_in[13];
  const float* xproj = (const float*)d_in[14];
  const float* dtw   = (const float*)d_in[15];
  const float* dtb   = (const float*)d_in[16];
  const float* A_log = (const float*)d_in[17];
  const float* Dp    = (const float*)d_in[18];
  const float* out_w = (const float*)d_in[19];
  const float* nfw   = (const float*)d_in[20];
  const float* nfb   = (const float*)d_in[21];
  const float* head_w= (const float*)d_in[22];
  const float* head_b= (const float*)d_in[23];
  float* out = (float*)d_out;

  float* ws = (float*)d_ws;
  float* resid = ws;  ws += (size_t)TB*DIMM;
  float* xz    = ws;  ws += (size_t)TB*2*DI;
  float* u     = ws;  ws += (size_t)TB*DI;
  float* dbc   = ws;  ws += (size_t)TB*64;      // padded N=64 layout
  float* wt_xp_f = ws; ws += (size_t)NL*64*512; // fp32 k4-packed xproj
  __bf16* xn_bf = (__bf16*)ws;  ws += (size_t)TB*DIMM/2;
  __bf16* yg_bf = (__bf16*)ws;  ws += (size_t)TB*DI/2;
  __bf16* wt_in = (__bf16*)ws;  ws += (size_t)NL*1024*256/2;
  __bf16* wt_out= (__bf16*)ws;  ws += (size_t)NL*256*512/2;
  __bf16* wt_pe = (__bf16*)ws;  ws += (size_t)256*768/2;
  // aliases (lifetimes don't overlap):
  __bf16* xp_bf = (__bf16*)xz;   // 3136*768 bf16 fits in xz
  float*  pemb  = u;             // 3136*256 fp32 fits in u

  // ---- weight prep: single merged dispatch (graph-safe) ----
  prep_weights<<<3520, 256, 0, stream>>>(in_w, out_w, pe_w, xproj,
                                          wt_in, wt_out, wt_pe, wt_xp_f);

  // ---- patch embed ----
  patch_ln1<<<NB*196, 256, 0, stream>>>(img, ln1g, ln1b, xp_bf);
  gemm_bf16<64,64,64><<<dim3(4, 49), 256, 0, stream>>>(
      xp_bf, wt_pe, pe_b, pemb, 3136, 256, 768);
  // fused: ln2 + pos + cls  AND  layer-0 residual init + LN -> xn_bf
  ln2_cls_pos<<<TB/4, 256, 0, stream>>>(pemb, ln2g, ln2b, pos, cls,
                                        resid, ln_w, ln_b, xn_bf);

  for (int i = 0; i < NL; i++){
    gemm_bf16<64,128,64><<<dim3(8, 50), 256, 0, stream>>>(
        xn_bf, wt_in + (size_t)i*1024*256, nullptr, xz, TB, 1024, 256);
    conv_xproj<<<TB/8, 256, 0, stream>>>(
        xz, conv_w + i*DI*4, conv_b + i*DI, wt_xp_f + (size_t)i*64*512, u, dbc);
    scan_kernel<<<NB*64, 128, 0, stream>>>(
        u, dbc, xz, A_log + i*DI*DS, Dp + i*DI, dtw + i*16*DI, dtb + i*DI, yg_bf);
    if (i < NL-1)
      gemm_out_fused<1><<<TB/16, 512, 0, stream>>>(
          yg_bf, wt_out + (size_t)i*256*512, resid, xn_bf,
          ln_w + (i+1)*DIMM, ln_b + (i+1)*DIMM);
    else
      gemm_out_fused<0><<<TB/16, 512, 0, stream>>>(
          yg_bf, wt_out + (size_t)i*256*512, resid, nullptr, nullptr, nullptr);
  }
  final_head<<<(1000+31)/32, 256, 0, stream>>>(resid, nfw, nfb, head_w, head_b, out);
}

// Round 8
// 634.367 us; speedup vs baseline: 1.0773x; 1.0773x over previous
//
#include <hip/hip_runtime.h>
#include <math.h>

#define NB   16      // batch
#define SEQL 197     // sequence length (196 patches + cls)
#define TB   (NB*SEQL)   // 3152 tokens
#define DIMM 256
#define DI   512
#define DS   16
#define NL   8

typedef __bf16 bf16x8 __attribute__((ext_vector_type(8)));
typedef __bf16 bf16x4 __attribute__((ext_vector_type(4)));
typedef float floatx4 __attribute__((ext_vector_type(4)));

// ---------------- block-wide 2-value reduction (256 threads = 4 waves) -----
__device__ __forceinline__ void block_reduce_2(float& s1, float& s2, float* red, int tid){
  #pragma unroll
  for (int off = 32; off > 0; off >>= 1){
    s1 += __shfl_down(s1, off, 64);
    s2 += __shfl_down(s2, off, 64);
  }
  __syncthreads();
  if ((tid & 63) == 0){ red[(tid>>6)*2] = s1; red[(tid>>6)*2+1] = s2; }
  __syncthreads();
  s1 = red[0] + red[2] + red[4] + red[6];
  s2 = red[1] + red[3] + red[5] + red[7];
}

// ---------------- merged weight prep: all transposes in ONE dispatch -------
// bf16 ranges: in[K][Nin] fp32 -> out[Nin][K] bf16.
// xproj range: in[512][48] fp32 -> out k4-packed fp32 [128][64][4]:
//   element (k,col) at (k>>2)*256 + col*4 + (k&3); cols 48..63 zero.
// Block ranges: [0,2048) in_w | [2048,3072) out_w | [3072,3264) pe_w |
//               [3264,3520) xproj
__global__ __launch_bounds__(256) void prep_weights(
    const float* __restrict__ in_w, const float* __restrict__ out_w,
    const float* __restrict__ pe_w, const float* __restrict__ xproj,
    __bf16* __restrict__ wt_in, __bf16* __restrict__ wt_out,
    __bf16* __restrict__ wt_pe, float* __restrict__ wt_xp_f)
{
  __shared__ float t[32][33];
  int bid = blockIdx.x;
  const float* src; __bf16* dst = nullptr; float* dstf = nullptr;
  int K, Nin, n0, k0;
  if (bid < 2048){                       // in_w: 8 z * (32 n-tiles * 8 k-tiles)
    int z = bid >> 8, tt = bid & 255;
    K = 256; Nin = 1024; n0 = (tt & 31)*32; k0 = (tt >> 5)*32;
    src = in_w  + (size_t)z*K*Nin;
    dst = wt_in + (size_t)z*K*Nin;
  } else if (bid < 3072){                // out_w: 8 z * (8 n-tiles * 16 k-tiles)
    int t2 = bid - 2048; int z = t2 >> 7, tt = t2 & 127;
    K = 512; Nin = 256; n0 = (tt & 7)*32; k0 = (tt >> 3)*32;
    src = out_w  + (size_t)z*K*Nin;
    dst = wt_out + (size_t)z*K*Nin;
  } else if (bid < 3264){                // pe_w: 8 n-tiles * 24 k-tiles
    int tt = bid - 3072;
    K = 768; Nin = 256; n0 = (tt & 7)*32; k0 = (tt >> 3)*32;
    src = pe_w; dst = wt_pe;
  } else {                               // xproj: 8 z * (2 n-tiles * 16 k-tiles)
    int t2 = bid - 3264; int z = t2 >> 5, tt = t2 & 31;
    K = 512; Nin = 48; n0 = (tt & 1)*32; k0 = (tt >> 1)*32;
    src  = xproj + (size_t)z*K*Nin;
    dstf = wt_xp_f + (size_t)z*64*512;
  }
  int tx = threadIdx.x & 31, ty = threadIdx.x >> 5;
  #pragma unroll
  for (int j = 0; j < 4; j++){
    int n = n0 + tx;
    t[ty + j*8][tx] = (n < Nin) ? src[(size_t)(k0 + ty + j*8)*Nin + n] : 0.f;
  }
  __syncthreads();
  if (dstf){
    #pragma unroll
    for (int j = 0; j < 4; j++){
      int k = k0 + tx, c = n0 + ty + j*8;
      dstf[(size_t)(k>>2)*256 + c*4 + (k&3)] = t[tx][ty + j*8];
    }
  } else {
    #pragma unroll
    for (int j = 0; j < 4; j++)
      dst[(size_t)(n0 + ty + j*8)*K + k0 + tx] = (__bf16)t[tx][ty + j*8];
  }
}

// ---------------- bf16 MFMA GEMM: C fp32 = A[M][K] @ Wt[N][K]^T (+bias) ----
// R6 known-good BK=32 inner loop (RESTORED -- R7's BK=64 manual prefetch
// regressed ~5us/dispatch: register pressure + replaced the compiler's own
// pipelining of this loop).
template<int BM, int BN, int KS>
__global__ __launch_bounds__(256) void gemm_bf16(
    const __bf16* __restrict__ A, const __bf16* __restrict__ Wt,
    const float* __restrict__ bias, float* __restrict__ C, int M, int N, int K)
{
  constexpr int BK  = 32;
  constexpr int LDA = BK + 8;
  constexpr int TMW = BM/32;
  constexpr int TNW = BN/32;
  __shared__ __bf16 As[BM][LDA];
  __shared__ __bf16 Bs[BN][LDA];

  int tid  = threadIdx.x;
  int lane = tid & 63, w = tid >> 6;
  int wm = w >> 1, wn = w & 1;
  int l15 = lane & 15, quad = lane >> 4;
  int nt = blockIdx.x / KS, ks = blockIdx.x % KS;
  int bm = blockIdx.y * BM, bn = nt * BN;
  int kbeg = ks * (K / KS), kend = kbeg + (K / KS);

  floatx4 acc[TMW][TNW] = {};

  for (int k0 = kbeg; k0 < kend; k0 += BK){
    #pragma unroll
    for (int i = 0; i < BM/64; i++){
      int c = tid + i*256;
      int row = c >> 2, kc = c & 3;
      int m = bm + row;
      uint4 v = make_uint4(0,0,0,0);
      if (m < M) v = ((const uint4*)(A + (size_t)m*K + k0))[kc];
      *(uint4*)&As[row][kc*8] = v;
    }
    #pragma unroll
    for (int i = 0; i < BN/64; i++){
      int c = tid + i*256;
      int row = c >> 2, kc = c & 3;
      int n = bn + row;
      uint4 v = ((const uint4*)(Wt + (size_t)n*K + k0))[kc];
      *(uint4*)&Bs[row][kc*8] = v;
    }
    __syncthreads();
    bf16x8 af[TMW], bf[TNW];
    #pragma unroll
    for (int mi = 0; mi < TMW; mi++)
      af[mi] = *(const bf16x8*)&As[wm*(BM/2) + mi*16 + l15][quad*8];
    #pragma unroll
    for (int ni = 0; ni < TNW; ni++)
      bf[ni] = *(const bf16x8*)&Bs[wn*(BN/2) + ni*16 + l15][quad*8];
    #pragma unroll
    for (int mi = 0; mi < TMW; mi++)
      #pragma unroll
      for (int ni = 0; ni < TNW; ni++)
        acc[mi][ni] = __builtin_amdgcn_mfma_f32_16x16x32_bf16(af[mi], bf[ni], acc[mi][ni], 0, 0, 0);
    __syncthreads();
  }
  #pragma unroll
  for (int mi = 0; mi < TMW; mi++){
    #pragma unroll
    for (int ni = 0; ni < TNW; ni++){
      int col = bn + wn*(BN/2) + ni*16 + l15;
      float bv = (KS == 1 && bias) ? bias[col] : 0.f;
      #pragma unroll
      for (int r = 0; r < 4; r++){
        int row = bm + wm*(BM/2) + mi*16 + quad*4 + r;
        if (row < M){
          if (KS == 1) C[(size_t)row*N + col] = acc[mi][ni][r] + bv;
          else         atomicAdd(&C[(size_t)row*N + col], acc[mi][ni][r]);
        }
      }
    }
  }
}

// ---------------- fused out-proj GEMM + residual add + next-layer LN -------
// y[16][256] = A[bm:bm+16][512] @ Wt[256][512]^T ; resid += y ;
// DO_LN: xn_bf = LN(resid)*g + b (bf16). 512 threads (8 waves), BK=64.
template<int DO_LN>
__global__ __launch_bounds__(512) void gemm_out_fused(
    const __bf16* __restrict__ A, const __bf16* __restrict__ Wt,
    float* __restrict__ resid, __bf16* __restrict__ xn_bf,
    const float* __restrict__ g, const float* __restrict__ bta)
{
  constexpr int BK = 64, LDA = BK + 8;      // 72
  __shared__ alignas(16) char smem[(16 + 256) * LDA * sizeof(__bf16)]; // 39168B
  __bf16 (*As)[LDA] = (__bf16(*)[LDA])smem;
  __bf16 (*Bs)[LDA] = (__bf16(*)[LDA])(smem + 16*LDA*sizeof(__bf16));
  float  (*sy)[264] = (float(*)[264])smem;  // union reuse: 16*264*4 = 16896B

  int tid = threadIdx.x, lane = tid & 63, w = tid >> 6;   // w in 0..7
  int l15 = lane & 15, quad = lane >> 4;
  int bm = blockIdx.x * 16;

  floatx4 acc[2] = {};
  for (int k0 = 0; k0 < 512; k0 += BK){
    if (tid < 128){                        // A: 16 rows x 8 uint4
      int row = tid >> 3, kc = tid & 7;
      *(uint4*)&As[row][kc*8] = ((const uint4*)(A + (size_t)(bm+row)*512 + k0))[kc];
    }
    #pragma unroll
    for (int i = 0; i < 4; i++){           // B: 256 rows x 8 uint4 = 2048
      int c = tid + i*512;
      int row = c >> 3, kc = c & 7;
      *(uint4*)&Bs[row][kc*8] = ((const uint4*)(Wt + (size_t)row*512 + k0))[kc];
    }
    __syncthreads();
    #pragma unroll
    for (int kk = 0; kk < 2; kk++){
      bf16x8 af = *(const bf16x8*)&As[l15][kk*32 + quad*8];
      #pragma unroll
      for (int ni = 0; ni < 2; ni++){
        bf16x8 bfv = *(const bf16x8*)&Bs[w*32 + ni*16 + l15][kk*32 + quad*8];
        acc[ni] = __builtin_amdgcn_mfma_f32_16x16x32_bf16(af, bfv, acc[ni], 0, 0, 0);
      }
    }
    __syncthreads();
  }
  // dump fragments to LDS (rows = quad*4+r, cols = w*32 + ni*16 + l15)
  #pragma unroll
  for (int ni = 0; ni < 2; ni++){
    int col = w*32 + ni*16 + l15;
    #pragma unroll
    for (int r = 0; r < 4; r++)
      sy[quad*4 + r][col] = acc[ni][r];
  }
  __syncthreads();
  // row-major pass: wave w owns rows w*2, w*2+1; coalesced float4
  #pragma unroll
  for (int rr = 0; rr < 2; rr++){
    int row = w*2 + rr;
    size_t base = (size_t)(bm + row)*256 + lane*4;
    float4 y4 = *(const float4*)&sy[row][lane*4];
    float4 rv = *(const float4*)&resid[base];
    float4 v;
    v.x = y4.x + rv.x; v.y = y4.y + rv.y; v.z = y4.z + rv.z; v.w = y4.w + rv.w;
    *(float4*)&resid[base] = v;
    if (DO_LN){
      float s  = v.x + v.y + v.z + v.w;
      float s2 = v.x*v.x + v.y*v.y + v.z*v.z + v.w*v.w;
      #pragma unroll
      for (int off = 1; off < 64; off <<= 1){
        s  += __shfl_xor(s,  off, 64);
        s2 += __shfl_xor(s2, off, 64);
      }
      float mu  = s * (1.f/256.f);
      float var = s2 * (1.f/256.f) - mu*mu;
      float rrq = rsqrtf(var + 1e-5f);
      float4 gv = *(const float4*)&g[lane*4];
      float4 bv = *(const float4*)&bta[lane*4];
      bf16x4 o;
      o[0] = (__bf16)((v.x - mu)*rrq*gv.x + bv.x);
      o[1] = (__bf16)((v.y - mu)*rrq*gv.y + bv.y);
      o[2] = (__bf16)((v.z - mu)*rrq*gv.z + bv.z);
      o[3] = (__bf16)((v.w - mu)*rrq*gv.w + bv.w);
      *(bf16x4*)&xn_bf[base] = o;
    }
  }
}

// ---------------- patch LN1: gather + LayerNorm(768) -> bf16 ---------------
// R7 map kept: tid <-> (p1 = tid>>4, p2 = tid&15), loop over channel c.
// Lanes read 16-float contiguous runs (64B segments) -> coalesced.
__global__ __launch_bounds__(256) void patch_ln1(
    const float* __restrict__ img, const float* __restrict__ g1, const float* __restrict__ b1,
    __bf16* __restrict__ xp_bf)
{
  __shared__ float red[8];
  int blk = blockIdx.x;            // b*196 + patch
  int b = blk / 196, p = blk % 196;
  int hh = p / 14, ww = p % 14;
  int tid = threadIdx.x;

  const float* ip = img + ((size_t)(b*3)*224 + hh*16 + (tid>>4))*224 + ww*16 + (tid&15);
  float v[3]; float s = 0.f, s2 = 0.f;
  #pragma unroll
  for (int c = 0; c < 3; c++){
    float val = ip[(size_t)c*224*224];
    v[c] = val; s += val; s2 += val*val;
  }
  block_reduce_2(s, s2, red, tid);
  float mu = s * (1.f/768.f);
  float var = s2 * (1.f/768.f) - mu*mu;
  float rr = rsqrtf(var + 1e-5f);
  #pragma unroll
  for (int c = 0; c < 3; c++){
    int e = tid*3 + c;
    xp_bf[(size_t)blk*768 + e] = (__bf16)((v[c] - mu) * rr * g1[e] + b1[e]);
  }
}

// ---------------- patch LN2 + pos + cls + layer-0 LN, wave-per-token -------
// R7 version kept: 788 blocks x 4 waves; each wave owns one token.
// Pure-shfl reductions, zero barriers. Writes resid + xn_bf.
__global__ __launch_bounds__(256) void ln2_cls_pos(
    const float* __restrict__ pemb, const float* __restrict__ g2, const float* __restrict__ b2,
    const float* __restrict__ pos, const float* __restrict__ cls,
    float* __restrict__ resid,
    const float* __restrict__ g0, const float* __restrict__ b0,
    __bf16* __restrict__ xn_bf)
{
  int w = threadIdx.x >> 6, lane = threadIdx.x & 63;
  int blk = blockIdx.x*4 + w;      // token id
  int b = blk / SEQL, l = blk % SEQL;
  int e = lane*4;
  float4 o;
  if (l == 0){
    float4 cv = *(const float4*)&cls[e];
    float4 pv = *(const float4*)&pos[e];
    o.x = cv.x + pv.x; o.y = cv.y + pv.y; o.z = cv.z + pv.z; o.w = cv.w + pv.w;
  } else {
    float4 v = *(const float4*)&pemb[(size_t)(b*196 + l-1)*256 + e];
    float s  = v.x + v.y + v.z + v.w;
    float s2 = v.x*v.x + v.y*v.y + v.z*v.z + v.w*v.w;
    #pragma unroll
    for (int off = 1; off < 64; off <<= 1){
      s  += __shfl_xor(s,  off, 64);
      s2 += __shfl_xor(s2, off, 64);
    }
    float mu  = s * (1.f/256.f);
    float var = s2 * (1.f/256.f) - mu*mu;
    float rr  = rsqrtf(var + 1e-5f);
    float4 gv = *(const float4*)&g2[e];
    float4 bv = *(const float4*)&b2[e];
    float4 pv = *(const float4*)&pos[l*256 + e];
    o.x = (v.x - mu)*rr*gv.x + bv.x + pv.x;
    o.y = (v.y - mu)*rr*gv.y + bv.y + pv.y;
    o.z = (v.z - mu)*rr*gv.z + bv.z + pv.z;
    o.w = (v.w - mu)*rr*gv.w + bv.w + pv.w;
  }
  size_t idx = (size_t)blk*256 + e;
  *(float4*)&resid[idx] = o;
  // layer-0 LN
  float s  = o.x + o.y + o.z + o.w;
  float s2 = o.x*o.x + o.y*o.y + o.z*o.z + o.w*o.w;
  #pragma unroll
  for (int off = 1; off < 64; off <<= 1){
    s  += __shfl_xor(s,  off, 64);
    s2 += __shfl_xor(s2, off, 64);
  }
  float mu  = s * (1.f/256.f);
  float var = s2 * (1.f/256.f) - mu*mu;
  float rr  = rsqrtf(var + 1e-5f);
  float4 gv = *(const float4*)&g0[e];
  float4 bv = *(const float4*)&b0[e];
  bf16x4 ob;
  ob[0] = (__bf16)((o.x - mu)*rr*gv.x + bv.x);
  ob[1] = (__bf16)((o.y - mu)*rr*gv.y + bv.y);
  ob[2] = (__bf16)((o.z - mu)*rr*gv.z + bv.z);
  ob[3] = (__bf16)((o.w - mu)*rr*gv.w + bv.w);
  *(bf16x4*)&xn_bf[idx] = ob;
}

// ---------------- FUSED causal conv(k=4)+SiLU + xproj matvec (R6) ----------
// Block = 8 tokens, 256 threads. Phase 1: conv+SiLU -> u (global) + LDS,
// sliding-window history in registers (7 global loads/thread vs 16).
// Phase 2: dbc[t][0:48] = u[t][:] @ xproj, k4-packed coalesced weight.
__global__ __launch_bounds__(256) void conv_xproj(
    const float* __restrict__ xz, const float* __restrict__ cw, const float* __restrict__ cb,
    const float* __restrict__ wxp,
    float* __restrict__ u, float* __restrict__ dbc)
{
  __shared__ float s_u[8][512];         // 16 KB
  __shared__ float s_acc[4][8][64];     // 8 KB
  int tid = threadIdx.x;
  int t0 = blockIdx.x * 8;

  // ---- phase 1: conv + silu, sliding window ----
  int d = (tid & 127) * 4;
  float4 w0 = *(const float4*)&cw[(d+0)*4];
  float4 w1 = *(const float4*)&cw[(d+1)*4];
  float4 w2 = *(const float4*)&cw[(d+2)*4];
  float4 w3 = *(const float4*)&cw[(d+3)*4];
  float4 cbv = *(const float4*)&cb[d];
  const float4 z4 = make_float4(0.f,0.f,0.f,0.f);
  int tt0 = t0 + (tid >> 7)*4;          // first of this thread's 4 tokens
  float4 h1 = (tt0 >= 1) ? *(const float4*)&xz[(size_t)(tt0-1)*1024 + d] : z4;
  float4 h2 = (tt0 >= 2) ? *(const float4*)&xz[(size_t)(tt0-2)*1024 + d] : z4;
  float4 h3 = (tt0 >= 3) ? *(const float4*)&xz[(size_t)(tt0-3)*1024 + d] : z4;
  int l0 = tt0 % SEQL;
  #pragma unroll
  for (int j = 0; j < 4; j++){
    int t = tt0 + j;
    int l = l0 + j; if (l >= SEQL) l -= SEQL;
    float4 x0 = *(const float4*)&xz[(size_t)t*1024 + d];
    float4 x1 = (l>=1) ? h1 : z4;
    float4 x2 = (l>=2) ? h2 : z4;
    float4 x3 = (l>=3) ? h3 : z4;
    float4 r = cbv;
    r.x += x3.x*w0.x + x2.x*w0.y + x1.x*w0.z + x0.x*w0.w;
    r.y += x3.y*w1.x + x2.y*w1.y + x1.y*w1.z + x0.y*w1.w;
    r.z += x3.z*w2.x + x2.z*w2.y + x1.z*w2.z + x0.z*w2.w;
    r.w += x3.w*w3.x + x2.w*w3.y + x1.w*w3.z + x0.w*w3.w;
    r.x *= 1.f/(1.f + __expf(-r.x));
    r.y *= 1.f/(1.f + __expf(-r.y));
    r.z *= 1.f/(1.f + __expf(-r.z));
    r.w *= 1.f/(1.f + __expf(-r.w));
    *(float4*)&u[(size_t)t*512 + d] = r;
    *(float4*)&s_u[(tid>>7)*4 + j][d] = r;
    h3 = h2; h2 = h1; h1 = x0;
  }
  __syncthreads();

  // ---- phase 2: xproj matvec; wave = one 128-wide k-slice, lane = col ----
  int col = tid & 63, sl = tid >> 6;
  const float4* wp4 = (const float4*)wxp + (size_t)sl*32*64 + col;
  float a[8] = {};
  #pragma unroll 4
  for (int k4 = 0; k4 < 32; k4++){
    float4 wv = wp4[(size_t)k4*64];
    #pragma unroll
    for (int t = 0; t < 8; t++){
      float4 v = *(const float4*)&s_u[t][sl*128 + k4*4];
      a[t] += wv.x*v.x + wv.y*v.y + wv.z*v.z + wv.w*v.w;
    }
  }
  #pragma unroll
  for (int t = 0; t < 8; t++) s_acc[sl][t][col] = a[t];
  __syncthreads();
  #pragma unroll
  for (int j = 0; j < 2; j++){
    int p = tid + j*256;
    int tok = p >> 6, c2 = p & 63;
    if (c2 < 48){
      float v = s_acc[0][tok][c2] + s_acc[1][tok][c2]
              + s_acc[2][tok][c2] + s_acc[3][tok][c2];
      dbc[(size_t)(t0 + tok)*64 + c2] = v;
    }
  }
}

// ---------------- selective scan + fused dtproj/softplus (R3/R8) -----------
// dbc is [TB][64]: cols 0:16 dt_in, 16:32 B, 32:48 C.
#define SCT 32
#define NCH ((SEQL + SCT - 1)/SCT)   // 7
#define NDL 8                        // d-channels per block
__global__ __launch_bounds__(128) void scan_kernel(
    const float* __restrict__ u, const float* __restrict__ dbc,
    const float* __restrict__ xz, const float* __restrict__ A_log, const float* __restrict__ Dp,
    const float* __restrict__ dtw, const float* __restrict__ dtb,
    __bf16* __restrict__ yg_bf)
{
  __shared__ float s_D [16][36];        // dt_in  [k][tl]
  __shared__ float s_B [16][36];        // B      [n][tl]
  __shared__ float s_C [16][36];        // C      [n][tl]
  __shared__ float s_u [NDL][36];       // u      [dl][tl]
  __shared__ float s_z [NDL][36];       // z      [dl][tl]
  __shared__ float s_dt[NDL][36];       // softplus dt [dl][tl]
  __shared__ float s_yp[SCT][NDL][20];  // y partials [tl][dl][n]
  __shared__ float s_dp[NDL];

  int tid = threadIdx.x;                // 0..127 = dl*16 + n
  int n = tid & 15, dl = tid >> 4;      // dl 0..7
  int b = blockIdx.x >> 6, dg = blockIdx.x & 63;
  int d0 = dg * NDL;
  const size_t base = (size_t)b * SEQL;

  float A = -__expf(A_log[(d0+dl)*DS + n]);
  float h = 0.f;
  if (tid < NDL) s_dp[tid] = Dp[d0 + tid];
  int cch = tid & 7;                    // dt-proj output channel for this thread
  float wc[16];
  #pragma unroll
  for (int k = 0; k < 16; k++) wc[k] = dtw[k*512 + d0 + cch];
  float dtbv = dtb[d0 + cch];

  float r_u[2], r_z[2], r_db[12];
  auto load_regs = [&](int c){
    #pragma unroll
    for (int i = 0; i < 2; i++){
      int v = tid + i*128;
      int tg = c*SCT + (v>>3); if (tg > SEQL-1) tg = SEQL-1;
      size_t t = base + tg;
      r_u[i] = u [t*512 + d0 + (v&7)];
      r_z[i] = xz[t*1024 + 512 + d0 + (v&7)];
    }
    #pragma unroll
    for (int s = 0; s < 3; s++)
      #pragma unroll
      for (int i = 0; i < 4; i++){
        int v = tid + i*128;
        int tg = c*SCT + (v>>4); if (tg > SEQL-1) tg = SEQL-1;
        r_db[s*4+i] = dbc[(base + tg)*64 + s*16 + (v&15)];
      }
  };
  auto write_DBC = [&](){
    #pragma unroll
    for (int i = 0; i < 4; i++){
      int v = tid + i*128;
      s_D[v&15][v>>4] = r_db[0+i];
      s_B[v&15][v>>4] = r_db[4+i];
      s_C[v&15][v>>4] = r_db[8+i];
    }
  };
  auto write_UZ = [&](){
    #pragma unroll
    for (int i = 0; i < 2; i++){
      int v = tid + i*128;
      s_u[v&7][v>>3] = r_u[i];
      s_z[v&7][v>>3] = r_z[i];
    }
  };
  auto compute_dt = [&](){
    #pragma unroll
    for (int i = 0; i < 2; i++){
      int tl = (tid >> 3) + i*16;
      float acc = dtbv;
      #pragma unroll
      for (int k = 0; k < 16; k++) acc += s_D[k][tl] * wc[k];
      s_dt[cch][tl] = (acc > 20.f) ? acc : log1pf(__expf(acc));
    }
  };

  // prologue: stage chunk 0
  load_regs(0);
  write_DBC();
  write_UZ();
  __syncthreads();
  compute_dt();
  __syncthreads();

  for (int c = 0; c < NCH; c++){
    if (c + 1 < NCH) load_regs(c+1);        // global loads in flight over compute

    // ---- hot loop: 32 steps, unrolled, no cross-lane deps ----
    float4 dt4, u4, B4, C4;
    #pragma unroll
    for (int tl = 0; tl < SCT; tl++){
      if ((tl & 3) == 0){
        dt4 = *(const float4*)&s_dt[dl][tl];
        u4  = *(const float4*)&s_u [dl][tl];
        B4  = *(const float4*)&s_B [n][tl];
        C4  = *(const float4*)&s_C [n][tl];
      }
      float dtv = ((float*)&dt4)[tl&3];
      float uv  = ((float*)&u4 )[tl&3];
      float Bv  = ((float*)&B4 )[tl&3];
      float Cv  = ((float*)&C4 )[tl&3];
      h = __expf(dtv * A) * h + (dtv * uv) * Bv;
      s_yp[tl][dl][n] = h * Cv;
    }
    __syncthreads();                         // (1) y-partials visible

    if (c + 1 < NCH) write_DBC();            // stage next D/B/C

    // ---- reduction + gate + store ----
    #pragma unroll
    for (int j = 0; j < 2; j++){
      int p = tid + j*128;
      int tl = p >> 3, dr = p & 7;
      float4 a0 = *(const float4*)&s_yp[tl][dr][0];
      float4 a1 = *(const float4*)&s_yp[tl][dr][4];
      float4 a2 = *(const float4*)&s_yp[tl][dr][8];
      float4 a3 = *(const float4*)&s_yp[tl][dr][12];
      float yv = ((a0.x+a0.y)+(a0.z+a0.w)) + ((a1.x+a1.y)+(a1.z+a1.w))
               + ((a2.x+a2.y)+(a2.z+a2.w)) + ((a3.x+a3.y)+(a3.z+a3.w));
      int tg = c*SCT + tl;
      if (tg < SEQL){
        float uv = s_u[dr][tl];
        float zv = s_z[dr][tl];
        float sg = 1.f / (1.f + __expf(-zv));
        yg_bf[(base + tg)*512 + d0 + dr] = (__bf16)((yv + uv*s_dp[dr]) * zv * sg);
      }
    }
    __syncthreads();                         // (2) u/z reads done; s_D complete

    if (c + 1 < NCH){
      write_UZ();
      compute_dt();
      __syncthreads();                       // (3) s_dt/s_u/s_z ready
    }
  }
}

// ---------------- FUSED final LN (token 0) + head GEMM (R6) ----------------
__global__ __launch_bounds__(256) void final_head(
    const float* __restrict__ resid,
    const float* __restrict__ g, const float* __restrict__ bta,
    const float* __restrict__ head_w, const float* __restrict__ head_b,
    float* __restrict__ out)
{
  __shared__ float xs[16][256];
  int tid = threadIdx.x, lane = tid & 63, w = tid >> 6;
  #pragma unroll
  for (int rb = 0; rb < 4; rb++){
    int b = w + rb*4;
    const float* rp = resid + (size_t)b*SEQL*256;   // token 0
    float4 v = *(const float4*)&rp[lane*4];
    float s  = v.x + v.y + v.z + v.w;
    float s2 = v.x*v.x + v.y*v.y + v.z*v.z + v.w*v.w;
    #pragma unroll
    for (int off = 1; off < 64; off <<= 1){
      s  += __shfl_xor(s,  off, 64);
      s2 += __shfl_xor(s2, off, 64);
    }
    float mu  = s * (1.f/256.f);
    float var = s2 * (1.f/256.f) - mu*mu;
    float rr  = rsqrtf(var + 1e-5f);
    float4 gv = *(const float4*)&g[lane*4];
    float4 bv = *(const float4*)&bta[lane*4];
    xs[b][lane*4+0] = (v.x - mu)*rr*gv.x + bv.x;
    xs[b][lane*4+1] = (v.y - mu)*rr*gv.y + bv.y;
    xs[b][lane*4+2] = (v.z - mu)*rr*gv.z + bv.z;
    xs[b][lane*4+3] = (v.w - mu)*rr*gv.w + bv.w;
  }
  __syncthreads();
  int nl = tid & 31, bq = tid >> 5;
  int nn = blockIdx.x*32 + nl;
  if (nn >= 1000) return;
  float acc0 = 0.f, acc1 = 0.f;
  #pragma unroll 8
  for (int k = 0; k < 256; k++){
    float wv = head_w[k*1000 + nn];
    acc0 += xs[bq][k]   * wv;
    acc1 += xs[bq+8][k] * wv;
  }
  float hb = head_b[nn];
  out[(size_t)bq*1000 + nn]     = acc0 + hb;
  out[(size_t)(bq+8)*1000 + nn] = acc1 + hb;
}

// ---------------------------------------------------------------------------
extern "C" void kernel_launch(void* const* d_in, const int* in_sizes, int n_in,
                              void* d_out, int out_size, void* d_ws, size_t ws_size,
                              hipStream_t stream) {
  const float* img   = (const float*)d_in[0];
  const float* ln1g  = (const float*)d_in[1];
  const float* ln1b  = (const float*)d_in[2];
  const float* pe_w  = (const float*)d_in[3];
  const float* pe_b  = (const float*)d_in[4];
  const float* ln2g  = (const float*)d_in[5];
  const float* ln2b  = (const float*)d_in[6];
  const float* pos   = (const float*)d_in[7];
  const float* cls   = (const float*)d_in[8];
  const float* ln_w  = (const float*)d_in[9];
  const float* ln_b  = (const float*)d_in[10];
  const float* in_w  = (const float*)d_in[11];
  const float* conv_w= (const float*)d_in[12];
  const float* conv_b= (const float*)d_in[13];
  const float* xproj = (const float*)d_in[14];
  const float* dtw   = (const float*)d_in[15];
  const float* dtb   = (const float*)d_in[16];
  const float* A_log = (const float*)d_in[17];
  const float* Dp    = (const float*)d_in[18];
  const float* out_w = (const float*)d_in[19];
  const float* nfw   = (const float*)d_in[20];
  const float* nfb   = (const float*)d_in[21];
  const float* head_w= (const float*)d_in[22];
  const float* head_b= (const float*)d_in[23];
  float* out = (float*)d_out;

  float* ws = (float*)d_ws;
  float* resid = ws;  ws += (size_t)TB*DIMM;
  float* xz    = ws;  ws += (size_t)TB*2*DI;
  float* u     = ws;  ws += (size_t)TB*DI;
  float* dbc   = ws;  ws += (size_t)TB*64;      // padded N=64 layout
  float* wt_xp_f = ws; ws += (size_t)NL*64*512; // fp32 k4-packed xproj
  __bf16* xn_bf = (__bf16*)ws;  ws += (size_t)TB*DIMM/2;
  __bf16* yg_bf = (__bf16*)ws;  ws += (size_t)TB*DI/2;
  __bf16* wt_in = (__bf16*)ws;  ws += (size_t)NL*1024*256/2;
  __bf16* wt_out= (__bf16*)ws;  ws += (size_t)NL*256*512/2;
  __bf16* wt_pe = (__bf16*)ws;  ws += (size_t)256*768/2;
  // aliases (lifetimes don't overlap):
  __bf16* xp_bf = (__bf16*)xz;   // 3136*768 bf16 fits in xz
  float*  pemb  = u;             // 3136*256 fp32 fits in u

  // ---- weight prep: single merged dispatch (graph-safe) ----
  prep_weights<<<3520, 256, 0, stream>>>(in_w, out_w, pe_w, xproj,
                                          wt_in, wt_out, wt_pe, wt_xp_f);

  // ---- patch embed ----
  patch_ln1<<<NB*196, 256, 0, stream>>>(img, ln1g, ln1b, xp_bf);
  gemm_bf16<64,64,1><<<dim3(256/64, 3136/64), 256, 0, stream>>>(
      xp_bf, wt_pe, pe_b, pemb, 3136, 256, 768);
  // fused: ln2 + pos + cls  AND  layer-0 residual init + LN -> xn_bf
  ln2_cls_pos<<<TB/4, 256, 0, stream>>>(pemb, ln2g, ln2b, pos, cls,
                                        resid, ln_w, ln_b, xn_bf);

  for (int i = 0; i < NL; i++){
    gemm_bf16<64,128,1><<<dim3(1024/128, (TB+63)/64), 256, 0, stream>>>(
        xn_bf, wt_in + (size_t)i*1024*256, nullptr, xz, TB, 1024, 256);
    conv_xproj<<<TB/8, 256, 0, stream>>>(
        xz, conv_w + i*DI*4, conv_b + i*DI, wt_xp_f + (size_t)i*64*512, u, dbc);
    scan_kernel<<<NB*64, 128, 0, stream>>>(
        u, dbc, xz, A_log + i*DI*DS, Dp + i*DI, dtw + i*16*DI, dtb + i*DI, yg_bf);
    if (i < NL-1)
      gemm_out_fused<1><<<TB/16, 512, 0, stream>>>(
          yg_bf, wt_out + (size_t)i*256*512, resid, xn_bf,
          ln_w + (i+1)*DIMM, ln_b + (i+1)*DIMM);
    else
      gemm_out_fused<0><<<TB/16, 512, 0, stream>>>(
          yg_bf, wt_out + (size_t)i*256*512, resid, nullptr, nullptr, nullptr);
  }
  final_head<<<(1000+31)/32, 256, 0, stream>>>(resid, nfw, nfb, head_w, head_b, out);
}